// Round 18
// baseline (31.620 us; speedup 1.0000x reference)
//
#include <hip/hip_runtime.h>

typedef __attribute__((ext_vector_type(8))) short short8;   // 8 bf16 (4 VGPRs)
typedef __attribute__((ext_vector_type(4))) float f32x4;    // MFMA acc

#define NPTS 131072

__device__ inline unsigned short f2bf(float f) {
    unsigned u = __float_as_uint(f);
    u = (u + 0x7FFFu + ((u >> 16) & 1u)) >> 16;   // RNE
    return (unsigned short)u;
}

// ---------------- prep: R12-green verbatim ----------------------------------
__global__ __launch_bounds__(256) void prep_kernel(
    const float* __restrict__ Ws, const float* __restrict__ bs,
    const float* __restrict__ W1, const float* __restrict__ b1,
    const float* __restrict__ W2,
    unsigned short* __restrict__ w1t, unsigned short* __restrict__ w2t,
    float* __restrict__ beff)
{
    int t = blockIdx.x * 256 + threadIdx.x;
    if (t < 4096) {                       // W1effT[e][k], k: 0..15 qcf, 16..18 win, rest 0
        int e = t >> 5, k = t & 31;
        float v = 0.f;
        if (k < 16) {
#pragma unroll 16
            for (int d = 0; d < 128; ++d) v = fmaf(Ws[k*128 + d], W1[d*128 + e], v);
        } else if (k < 19) {
            v = W1[(128 + (k - 16))*128 + e];
        }
        w1t[e*32 + k] = f2bf(v);
    } else if (t < 8192) {                // W2T[e][k] = W2[k][e]
        int t2 = t - 4096;
        int e = t2 >> 7, k = t2 & 127;
        w2t[e*128 + k] = f2bf(W2[k*32 + e]);
    } else if (t < 8320) {                // beff[e] = b1[e] + bs @ W1[0:128]
        int e = t - 8192;
        float v = b1[e];
#pragma unroll 16
        for (int d = 0; d < 128; ++d) v = fmaf(bs[d], W1[d*128 + e], v);
        beff[e] = v;
    }
}

// ---------------- main fused kernel (R12 body; XCD-swizzled block id) -------
// One 16-point tile per wave (grid 2048). Bijective XCD swizzle: consecutive
// tiles stay on one XCD -> didx/dwin/out lines not duplicated across 8 L2s.
// Per-wave-private LDS region (no __syncthreads in main path):
//   X   @0     : 16 pts x 40 bf16 (stride 80 B)   = 1280 B
//   H1  @1280  : 16 pts x 136 bf16 (stride 272 B) = 4352 B
//   H2  @5632  : 16 pts x 33 f32                  = 2112 B
//   Wb  @7744  : 16x8 f32                         = 512 B
//   Ib  @8256  : 16x8 int                         = 512 B
#define WREG 8768

__global__ __launch_bounds__(256, 2) void decoder_kernel(
    const float* __restrict__ qcf, const int* __restrict__ didx,
    const float* __restrict__ dwin, const float* __restrict__ bones,
    const unsigned short* __restrict__ w1t, const unsigned short* __restrict__ w2t,
    const float* __restrict__ beff, const float* __restrict__ b2,
    const float* __restrict__ W3, const float* __restrict__ b3,
    float* __restrict__ out)
{
    __shared__ unsigned char lds[4 * WREG];
    __shared__ float sW3[27];

    const int tid = threadIdx.x;
    if (tid < 24) sW3[tid] = W3[tid];
    if (tid < 3)  sW3[24 + tid] = b3[tid];
    __syncthreads();

    const int wave = tid >> 6;
    const int lane = tid & 63;
    unsigned char* wbase = lds + wave * WREG;
    unsigned short* Xb  = (unsigned short*)(wbase);
    unsigned short* H1b = (unsigned short*)(wbase + 1280);
    float*          H2b = (float*)(wbase + 5632);
    float*          Wb  = (float*)(wbase + 7744);
    int*            Ib  = (int*)(wbase + 8256);

    const int q4  = lane >> 4;   // quarter-wave
    const int l16 = lane & 15;

    // hoisted wave-invariant weight fragments + biases
    short8 W1f[8]; float beffv[8];
#pragma unroll
    for (int dt = 0; dt < 8; ++dt) {
        W1f[dt]   = *(const short8*)(w1t + (dt*16 + l16)*32 + q4*8);
        beffv[dt] = beff[dt*16 + l16];
    }
    short8 W2f[2][4]; float b2v[2];
#pragma unroll
    for (int et = 0; et < 2; ++et) {
        b2v[et] = b2[et*16 + l16];
#pragma unroll
        for (int kt = 0; kt < 4; ++kt)
            W2f[et][kt] = *(const short8*)(w2t + (et*16 + l16)*128 + kt*32 + q4*8);
    }

    // bijective XCD swizzle (2048 % 8 == 0): sw = (b%8)*256 + b/8
    const int sw   = (blockIdx.x & 7) * 256 + (blockIdx.x >> 3);
    const int gw   = sw * 4 + wave;
    const int base = gw * 16;   // one 16-point tile per wave

    // ---- IDW weights: 2 passes x (8 pts x 8 k) -----------------------------
#pragma unroll
    for (int ph = 0; ph < 2; ++ph) {
        const int pl = ph*8 + (lane >> 3);
        const int k  = lane & 7;
        const int p  = base + pl;
        const int id = didx[p*8 + k];
        const float bx = bones[id*3+0], by = bones[id*3+1], bz = bones[id*3+2];
        const float rx = dwin[p*3+0] - bx;
        const float ry = dwin[p*3+1] - by;
        const float rz = dwin[p*3+2] - bz;
        const float dist = sqrtf(fmaf(rx,rx, fmaf(ry,ry, fmaf(rz,rz, 1e-8f))));
        const float w = 1.0f / (dist + 1e-8f);
        float s = w;
        s += __shfl_xor(s, 1);
        s += __shfl_xor(s, 2);
        s += __shfl_xor(s, 4);
        Wb[pl*8 + k] = w / s;
        Ib[pl*8 + k] = id;
    }

    // ---- interp in qcf(16) space: 4 passes x 4 pts, build X bf16 -----------
#pragma unroll
    for (int ps = 0; ps < 4; ++ps) {
        const int pl = ps*4 + q4;
        const int4   i0 = *(const int4*)(Ib + pl*8);
        const int4   i1 = *(const int4*)(Ib + pl*8 + 4);
        const float4 w0 = *(const float4*)(Wb + pl*8);
        const float4 w1 = *(const float4*)(Wb + pl*8 + 4);
        float acc = 0.f;
        acc = fmaf(w0.x, qcf[i0.x*16 + l16], acc);
        acc = fmaf(w0.y, qcf[i0.y*16 + l16], acc);
        acc = fmaf(w0.z, qcf[i0.z*16 + l16], acc);
        acc = fmaf(w0.w, qcf[i0.w*16 + l16], acc);
        acc = fmaf(w1.x, qcf[i1.x*16 + l16], acc);
        acc = fmaf(w1.y, qcf[i1.y*16 + l16], acc);
        acc = fmaf(w1.z, qcf[i1.z*16 + l16], acc);
        acc = fmaf(w1.w, qcf[i1.w*16 + l16], acc);
        Xb[pl*40 + l16] = f2bf(acc);
        float wv = 0.f;
        if (l16 < 3) wv = dwin[(base + pl)*3 + l16];
        Xb[pl*40 + 16 + l16] = f2bf(wv);        // k=16..18 win, 19..31 zero
    }

    // ---- layer 1: [16 x 32] @ [32 x 128] via 8 MFMA ------------------------
    const short8 a1 = *(const short8*)(Xb + l16*40 + q4*8);
    f32x4 acc1[8];
#pragma unroll
    for (int dt = 0; dt < 8; ++dt) {
        f32x4 c = { beffv[dt], beffv[dt], beffv[dt], beffv[dt] };
        acc1[dt] = __builtin_amdgcn_mfma_f32_16x16x32_bf16(a1, W1f[dt], c, 0, 0, 0);
    }
#pragma unroll
    for (int dt = 0; dt < 8; ++dt) {
#pragma unroll
        for (int r = 0; r < 4; ++r) {
            const float h = fmaxf(acc1[dt][r], 0.f);
            H1b[(q4*4 + r)*136 + dt*16 + l16] = f2bf(h);
        }
    }

    // ---- layer 2: [16 x 128] @ [128 x 32] via 8 MFMA -----------------------
    f32x4 acc2[2] = { { b2v[0], b2v[0], b2v[0], b2v[0] },
                      { b2v[1], b2v[1], b2v[1], b2v[1] } };
#pragma unroll
    for (int kt = 0; kt < 4; ++kt) {
        const short8 a2 = *(const short8*)(H1b + l16*136 + kt*32 + q4*8);
        acc2[0] = __builtin_amdgcn_mfma_f32_16x16x32_bf16(a2, W2f[0][kt], acc2[0], 0, 0, 0);
        acc2[1] = __builtin_amdgcn_mfma_f32_16x16x32_bf16(a2, W2f[1][kt], acc2[1], 0, 0, 0);
    }
#pragma unroll
    for (int et = 0; et < 2; ++et) {
#pragma unroll
        for (int r = 0; r < 4; ++r) {
            H2b[(q4*4 + r)*33 + et*16 + l16] = fmaxf(acc2[et][r], 0.f);
        }
    }

    // ---- layer 3 (8->3 x4) + residual + store ------------------------------
#pragma unroll
    for (int i3 = 0; i3 < 3; ++i3) {
        const int g  = i3*64 + lane;      // 0..191 = 16 pts x 12
        const int pt = g / 12;
        const int q  = g - pt*12;
        const int r  = q / 3;
        const int o  = q - r*3;
        float acc = sW3[24 + o];
#pragma unroll
        for (int f = 0; f < 8; ++f)
            acc = fmaf(H2b[pt*33 + r*8 + f], sW3[f*3 + o], acc);
        const float wv = dwin[(base + pt)*3 + o];
        out[(size_t)base*12 + g] = wv + acc;
    }
}

extern "C" void kernel_launch(void* const* d_in, const int* in_sizes, int n_in,
                              void* d_out, int out_size, void* d_ws, size_t ws_size,
                              hipStream_t stream) {
    const float* qcf   = (const float*)d_in[0];
    const int*   didx  = (const int*)  d_in[1];
    const float* dwin  = (const float*)d_in[2];
    const float* bones = (const float*)d_in[3];
    // d_in[4] = K (always 8)
    const float* Ws = (const float*)d_in[5];
    const float* bs = (const float*)d_in[6];
    const float* W1 = (const float*)d_in[7];
    const float* b1 = (const float*)d_in[8];
    const float* W2 = (const float*)d_in[9];
    const float* b2 = (const float*)d_in[10];
    const float* W3 = (const float*)d_in[11];
    const float* b3 = (const float*)d_in[12];
    float* out = (float*)d_out;

    unsigned short* w1t  = (unsigned short*)d_ws;                    // 8 KB
    unsigned short* w2t  = (unsigned short*)((char*)d_ws + 8192);    // 8 KB
    float*          beff = (float*)((char*)d_ws + 16384);            // 512 B

    hipLaunchKernelGGL(prep_kernel, dim3(33), dim3(256), 0, stream,
                       Ws, bs, W1, b1, W2, w1t, w2t, beff);
    hipLaunchKernelGGL(decoder_kernel, dim3(2048), dim3(256), 0, stream,
                       qcf, didx, dwin, bones, w1t, w2t, beff, b2, W3, b3, out);
}

// Round 19
// 31.282 us; speedup vs baseline: 1.0108x; 1.0108x over previous
//
#include <hip/hip_runtime.h>

typedef __attribute__((ext_vector_type(8))) short short8;   // 8 bf16 (4 VGPRs)
typedef __attribute__((ext_vector_type(4))) float f32x4;    // MFMA acc

#define NPTS 131072

__device__ inline unsigned short f2bf(float f) {
    unsigned u = __float_as_uint(f);
    u = (u + 0x7FFFu + ((u >> 16) & 1u)) >> 16;   // RNE
    return (unsigned short)u;
}

// ---------------- prep: R12 verbatim (best green: 31.246 us) ----------------
__global__ __launch_bounds__(256) void prep_kernel(
    const float* __restrict__ Ws, const float* __restrict__ bs,
    const float* __restrict__ W1, const float* __restrict__ b1,
    const float* __restrict__ W2,
    unsigned short* __restrict__ w1t, unsigned short* __restrict__ w2t,
    float* __restrict__ beff)
{
    int t = blockIdx.x * 256 + threadIdx.x;
    if (t < 4096) {                       // W1effT[e][k], k: 0..15 qcf, 16..18 win, rest 0
        int e = t >> 5, k = t & 31;
        float v = 0.f;
        if (k < 16) {
#pragma unroll 16
            for (int d = 0; d < 128; ++d) v = fmaf(Ws[k*128 + d], W1[d*128 + e], v);
        } else if (k < 19) {
            v = W1[(128 + (k - 16))*128 + e];
        }
        w1t[e*32 + k] = f2bf(v);
    } else if (t < 8192) {                // W2T[e][k] = W2[k][e]
        int t2 = t - 4096;
        int e = t2 >> 7, k = t2 & 127;
        w2t[e*128 + k] = f2bf(W2[k*32 + e]);
    } else if (t < 8320) {                // beff[e] = b1[e] + bs @ W1[0:128]
        int e = t - 8192;
        float v = b1[e];
#pragma unroll 16
        for (int d = 0; d < 128; ++d) v = fmaf(bs[d], W1[d*128 + e], v);
        beff[e] = v;
    }
}

// ---------------- main fused kernel (R12 verbatim) --------------------------
// One 16-point tile per wave (grid 2048).
// Per-wave-private LDS region (no __syncthreads in main path):
//   X   @0     : 16 pts x 40 bf16 (stride 80 B)   = 1280 B
//   H1  @1280  : 16 pts x 136 bf16 (stride 272 B) = 4352 B
//   H2  @5632  : 16 pts x 33 f32                  = 2112 B
//   Wb  @7744  : 16x8 f32                         = 512 B
//   Ib  @8256  : 16x8 int                         = 512 B
#define WREG 8768

__global__ __launch_bounds__(256, 2) void decoder_kernel(
    const float* __restrict__ qcf, const int* __restrict__ didx,
    const float* __restrict__ dwin, const float* __restrict__ bones,
    const unsigned short* __restrict__ w1t, const unsigned short* __restrict__ w2t,
    const float* __restrict__ beff, const float* __restrict__ b2,
    const float* __restrict__ W3, const float* __restrict__ b3,
    float* __restrict__ out)
{
    __shared__ unsigned char lds[4 * WREG];
    __shared__ float sW3[27];

    const int tid = threadIdx.x;
    if (tid < 24) sW3[tid] = W3[tid];
    if (tid < 3)  sW3[24 + tid] = b3[tid];
    __syncthreads();

    const int wave = tid >> 6;
    const int lane = tid & 63;
    unsigned char* wbase = lds + wave * WREG;
    unsigned short* Xb  = (unsigned short*)(wbase);
    unsigned short* H1b = (unsigned short*)(wbase + 1280);
    float*          H2b = (float*)(wbase + 5632);
    float*          Wb  = (float*)(wbase + 7744);
    int*            Ib  = (int*)(wbase + 8256);

    const int q4  = lane >> 4;   // quarter-wave
    const int l16 = lane & 15;

    // hoisted wave-invariant weight fragments + biases
    short8 W1f[8]; float beffv[8];
#pragma unroll
    for (int dt = 0; dt < 8; ++dt) {
        W1f[dt]   = *(const short8*)(w1t + (dt*16 + l16)*32 + q4*8);
        beffv[dt] = beff[dt*16 + l16];
    }
    short8 W2f[2][4]; float b2v[2];
#pragma unroll
    for (int et = 0; et < 2; ++et) {
        b2v[et] = b2[et*16 + l16];
#pragma unroll
        for (int kt = 0; kt < 4; ++kt)
            W2f[et][kt] = *(const short8*)(w2t + (et*16 + l16)*128 + kt*32 + q4*8);
    }

    const int gw   = blockIdx.x * 4 + wave;
    const int base = gw * 16;   // one 16-point tile per wave

    // ---- IDW weights: 2 passes x (8 pts x 8 k) -----------------------------
#pragma unroll
    for (int ph = 0; ph < 2; ++ph) {
        const int pl = ph*8 + (lane >> 3);
        const int k  = lane & 7;
        const int p  = base + pl;
        const int id = didx[p*8 + k];
        const float bx = bones[id*3+0], by = bones[id*3+1], bz = bones[id*3+2];
        const float rx = dwin[p*3+0] - bx;
        const float ry = dwin[p*3+1] - by;
        const float rz = dwin[p*3+2] - bz;
        const float dist = sqrtf(fmaf(rx,rx, fmaf(ry,ry, fmaf(rz,rz, 1e-8f))));
        const float w = 1.0f / (dist + 1e-8f);
        float s = w;
        s += __shfl_xor(s, 1);
        s += __shfl_xor(s, 2);
        s += __shfl_xor(s, 4);
        Wb[pl*8 + k] = w / s;
        Ib[pl*8 + k] = id;
    }

    // ---- interp in qcf(16) space: 4 passes x 4 pts, build X bf16 -----------
#pragma unroll
    for (int ps = 0; ps < 4; ++ps) {
        const int pl = ps*4 + q4;
        const int4   i0 = *(const int4*)(Ib + pl*8);
        const int4   i1 = *(const int4*)(Ib + pl*8 + 4);
        const float4 w0 = *(const float4*)(Wb + pl*8);
        const float4 w1 = *(const float4*)(Wb + pl*8 + 4);
        float acc = 0.f;
        acc = fmaf(w0.x, qcf[i0.x*16 + l16], acc);
        acc = fmaf(w0.y, qcf[i0.y*16 + l16], acc);
        acc = fmaf(w0.z, qcf[i0.z*16 + l16], acc);
        acc = fmaf(w0.w, qcf[i0.w*16 + l16], acc);
        acc = fmaf(w1.x, qcf[i1.x*16 + l16], acc);
        acc = fmaf(w1.y, qcf[i1.y*16 + l16], acc);
        acc = fmaf(w1.z, qcf[i1.z*16 + l16], acc);
        acc = fmaf(w1.w, qcf[i1.w*16 + l16], acc);
        Xb[pl*40 + l16] = f2bf(acc);
        float wv = 0.f;
        if (l16 < 3) wv = dwin[(base + pl)*3 + l16];
        Xb[pl*40 + 16 + l16] = f2bf(wv);        // k=16..18 win, 19..31 zero
    }

    // ---- layer 1: [16 x 32] @ [32 x 128] via 8 MFMA ------------------------
    const short8 a1 = *(const short8*)(Xb + l16*40 + q4*8);
    f32x4 acc1[8];
#pragma unroll
    for (int dt = 0; dt < 8; ++dt) {
        f32x4 c = { beffv[dt], beffv[dt], beffv[dt], beffv[dt] };
        acc1[dt] = __builtin_amdgcn_mfma_f32_16x16x32_bf16(a1, W1f[dt], c, 0, 0, 0);
    }
#pragma unroll
    for (int dt = 0; dt < 8; ++dt) {
#pragma unroll
        for (int r = 0; r < 4; ++r) {
            const float h = fmaxf(acc1[dt][r], 0.f);
            H1b[(q4*4 + r)*136 + dt*16 + l16] = f2bf(h);
        }
    }

    // ---- layer 2: [16 x 128] @ [128 x 32] via 8 MFMA -----------------------
    f32x4 acc2[2] = { { b2v[0], b2v[0], b2v[0], b2v[0] },
                      { b2v[1], b2v[1], b2v[1], b2v[1] } };
#pragma unroll
    for (int kt = 0; kt < 4; ++kt) {
        const short8 a2 = *(const short8*)(H1b + l16*136 + kt*32 + q4*8);
        acc2[0] = __builtin_amdgcn_mfma_f32_16x16x32_bf16(a2, W2f[0][kt], acc2[0], 0, 0, 0);
        acc2[1] = __builtin_amdgcn_mfma_f32_16x16x32_bf16(a2, W2f[1][kt], acc2[1], 0, 0, 0);
    }
#pragma unroll
    for (int et = 0; et < 2; ++et) {
#pragma unroll
        for (int r = 0; r < 4; ++r) {
            H2b[(q4*4 + r)*33 + et*16 + l16] = fmaxf(acc2[et][r], 0.f);
        }
    }

    // ---- layer 3 (8->3 x4) + residual + store ------------------------------
#pragma unroll
    for (int i3 = 0; i3 < 3; ++i3) {
        const int g  = i3*64 + lane;      // 0..191 = 16 pts x 12
        const int pt = g / 12;
        const int q  = g - pt*12;
        const int r  = q / 3;
        const int o  = q - r*3;
        float acc = sW3[24 + o];
#pragma unroll
        for (int f = 0; f < 8; ++f)
            acc = fmaf(H2b[pt*33 + r*8 + f], sW3[f*3 + o], acc);
        const float wv = dwin[(base + pt)*3 + o];
        out[(size_t)base*12 + g] = wv + acc;
    }
}

extern "C" void kernel_launch(void* const* d_in, const int* in_sizes, int n_in,
                              void* d_out, int out_size, void* d_ws, size_t ws_size,
                              hipStream_t stream) {
    const float* qcf   = (const float*)d_in[0];
    const int*   didx  = (const int*)  d_in[1];
    const float* dwin  = (const float*)d_in[2];
    const float* bones = (const float*)d_in[3];
    // d_in[4] = K (always 8)
    const float* Ws = (const float*)d_in[5];
    const float* bs = (const float*)d_in[6];
    const float* W1 = (const float*)d_in[7];
    const float* b1 = (const float*)d_in[8];
    const float* W2 = (const float*)d_in[9];
    const float* b2 = (const float*)d_in[10];
    const float* W3 = (const float*)d_in[11];
    const float* b3 = (const float*)d_in[12];
    float* out = (float*)d_out;

    unsigned short* w1t  = (unsigned short*)d_ws;                    // 8 KB
    unsigned short* w2t  = (unsigned short*)((char*)d_ws + 8192);    // 8 KB
    float*          beff = (float*)((char*)d_ws + 16384);            // 512 B

    hipLaunchKernelGGL(prep_kernel, dim3(33), dim3(256), 0, stream,
                       Ws, bs, W1, b1, W2, w1t, w2t, beff);
    hipLaunchKernelGGL(decoder_kernel, dim3(2048), dim3(256), 0, stream,
                       qcf, didx, dwin, bones, w1t, w2t, beff, b2, W3, b3, out);
}